// Round 1
// 375.953 us; speedup vs baseline: 1.0649x; 1.0649x over previous
//
#include <hip/hip_runtime.h>

#define DEV __device__ __forceinline__

typedef __attribute__((ext_vector_type(8))) short bf16x8;   // 8 bf16 in 4 VGPRs
typedef __attribute__((ext_vector_type(4))) float f32x4;

constexpr int Bc  = 32;
constexpr int Nc  = 512;
constexpr int Dc  = 1024;
constexpr int Hc  = 16;
constexpr int HDc = 64;
constexpr int SEGc= 64;
constexpr int Mrows = Bc * Nc;          // 16384 rows for the big GEMMs

// round-to-nearest-even f32 -> bf16 bit pattern
DEV unsigned short bf16r(float x) {
  union { float f; unsigned int u; } c; c.f = x;
  unsigned int r = (c.u + 0x7fffu + ((c.u >> 16) & 1u)) >> 16;
  return (unsigned short)r;
}

// async global->LDS, 16B per lane. LDS dest must be wave-uniform base; HW
// scatters lane i to base + i*16. Global source IS per-lane.
DEV void async_ld16(const void* g, void* l) {
  __builtin_amdgcn_global_load_lds(
      (const __attribute__((address_space(1))) void*)g,
      (__attribute__((address_space(3))) void*)l,
      16, 0, 0);
}

// ------------------------------------------------------------- Wo transpose
// 1024x1024 f32 -> bf16 (dst[c][r] = src[r][c]) : row-major B^T for gemm_bt
__global__ void transpose_bf16(const float* __restrict__ src,
                               unsigned short* __restrict__ dst) {
  __shared__ float tile[32][33];
  int bx = blockIdx.x & 31, by = blockIdx.x >> 5;
  int tx = threadIdx.x & 31, ty = threadIdx.x >> 5;   // 32 x 8
  for (int i = 0; i < 4; ++i) {
    int r = ty + i * 8;
    tile[r][tx] = src[(size_t)(by * 32 + r) * 1024 + bx * 32 + tx];
  }
  __syncthreads();
  for (int i = 0; i < 4; ++i) {
    int r = ty + i * 8;
    dst[(size_t)(bx * 32 + r) * 1024 + by * 32 + tx] = bf16r(tile[tx][r]);
  }
}

// ------------------------------------------------------------- Wq tiling
// Wq f32 (k,c) -> WqTile bf16, MFMA-staging-ready layout:
//   short idx = (k>>5)*32768 + ((k>>3)&3)*8192 + c*8 + (k&7)
// i.e. per 32-k step a contiguous 64 KB tile [k-oct][c][8], so global_load_lds
// of the tile is a LINEAR copy and ds_read_b128 frags are 2-way-conflict free.
__global__ void wq_tile(const float* __restrict__ src,
                        unsigned short* __restrict__ dst) {
  __shared__ float tile[32][33];
  int bx = blockIdx.x & 31, by = blockIdx.x >> 5;     // bx: c-tile, by: k-tile
  int tx = threadIdx.x & 31, ty = threadIdx.x >> 5;   // 32 x 8
  for (int i = 0; i < 4; ++i) {
    int r = ty + i * 8;                               // k-local
    tile[r][tx] = src[(size_t)(by * 32 + r) * 1024 + bx * 32 + tx];
  }
  __syncthreads();
  if (ty < 4) {                       // 128 threads: one 16B unit each
    int oct = ty;                     // k-oct within this 32-k step
    unsigned short tmp[8];
#pragma unroll
    for (int e = 0; e < 8; ++e) tmp[e] = bf16r(tile[oct * 8 + e][tx]);
    ushort4 u0, u1;
    u0.x = tmp[0]; u0.y = tmp[1]; u0.z = tmp[2]; u0.w = tmp[3];
    u1.x = tmp[4]; u1.y = tmp[5]; u1.z = tmp[6]; u1.w = tmp[7];
    size_t idx = (size_t)by * 32768 + (size_t)oct * 8192 + (size_t)(bx * 32 + tx) * 8;
    *(ushort4*)(dst + idx) = u0;
    *(ushort4*)(dst + idx + 4) = u1;
  }
}

// ------------------------------------------------------------- router cvt
// router f32 (S=64, N=512, HD=64) -> per-n contiguous 8KB blocks:
//   Rg [n][s][oct^ (s&7)][e]  (R_n rows s, d-octs XOR-swizzled)
//   RTg[n][d][oct^ (d&7)][e]  (R_n^T rows d, s-octs XOR-swizzled)
// XOR baked into GLOBAL layout so global_load_lds stays linear; the fused
// kernel applies the same XOR on ds_read (T2 both-sides rule).
__global__ void cvt_router2(const float* __restrict__ src,
                            unsigned short* __restrict__ Rg,
                            unsigned short* __restrict__ RTg) {
  int nn = blockIdx.x;                 // 0..511
  int t  = threadIdx.x;                // 256
  int s  = t >> 2, dq = (t & 3) * 16;
  const float* p = src + ((size_t)s * 512 + nn) * 64 + dq;
  float v[16];
#pragma unroll
  for (int i = 0; i < 16; i += 4) {
    float4 f = *(const float4*)(p + i);
    v[i] = f.x; v[i+1] = f.y; v[i+2] = f.z; v[i+3] = f.w;
  }
  unsigned short bv[16];
#pragma unroll
  for (int i = 0; i < 16; ++i) bv[i] = bf16r(v[i]);
  unsigned short* rb = Rg + (size_t)nn * 4096 + s * 64;
#pragma unroll
  for (int o2 = 0; o2 < 2; ++o2) {
    int oct  = (dq >> 3) + o2;
    int phys = oct ^ (s & 7);
    ushort4 a, b2;
    a.x  = bv[o2*8+0]; a.y  = bv[o2*8+1]; a.z  = bv[o2*8+2]; a.w  = bv[o2*8+3];
    b2.x = bv[o2*8+4]; b2.y = bv[o2*8+5]; b2.z = bv[o2*8+6]; b2.w = bv[o2*8+7];
    *(ushort4*)(rb + phys * 8)     = a;
    *(ushort4*)(rb + phys * 8 + 4) = b2;
  }
  unsigned short* tb = RTg + (size_t)nn * 4096;
#pragma unroll
  for (int i = 0; i < 16; ++i) {
    int d = dq + i;
    tb[d * 64 + (((s >> 3) ^ (d & 7)) * 8) + (s & 7)] = bv[i];
  }
}

// ---------------------------------------------------------------- GEMM
// C(M x 1024) = A(M x 1024, bf16 row-major) * B + bias; B given as BT (1024 x 1024
// bf16 row-major, BT[n][k] = B[k][n]). OUT_F32: f32 out, else bf16 out.
template <bool OUT_F32>
__global__ __launch_bounds__(256)
void gemm_bt(const unsigned short* __restrict__ A,
             const unsigned short* __restrict__ BT,
             const float* __restrict__ bias,
             void* __restrict__ Cout) {
  constexpr int K = 1024, Nn = 1024, BM = 128, BK = 32;
  __shared__ unsigned short As[BM * BK];   // 8 KB
  __shared__ unsigned short Bs[BM * BK];   // 8 KB
  const int tid = threadIdx.x, lane = tid & 63, wave = tid >> 6;
  const int tm = blockIdx.x >> 3, tn = blockIdx.x & 7;
  const int wm = (wave >> 1) * 64, wn = (wave & 1) * 64;
  const int la = lane & 15, quad = lane >> 4, lb8 = quad * 8;

  f32x4 acc[4][4] = {};

  const int srow = tid >> 2;
  const int scol = (tid & 3) * 8;
  const unsigned short* Ag = A  + (size_t)(tm * BM + srow) * K + scol;
  const unsigned short* Bg = BT + (size_t)(tn * BM + srow) * K + scol;
  unsigned short* ldsA = As + wave * 512;
  unsigned short* ldsB = Bs + wave * 512;

  for (int k0 = 0; k0 < K; k0 += BK) {
    __syncthreads();
    async_ld16(Ag + k0,          ldsA);
    async_ld16(Ag + 64 * K + k0, ldsA + 2048);
    async_ld16(Bg + k0,          ldsB);
    async_ld16(Bg + 64 * K + k0, ldsB + 2048);
    __syncthreads();

    bf16x8 af[4], bfr[4];
#pragma unroll
    for (int i = 0; i < 4; ++i)
      af[i] = *(const bf16x8*)(As + (wm + i * 16 + la) * BK + lb8);
#pragma unroll
    for (int j = 0; j < 4; ++j)
      bfr[j] = *(const bf16x8*)(Bs + (wn + j * 16 + la) * BK + lb8);
#pragma unroll
    for (int i = 0; i < 4; ++i)
#pragma unroll
      for (int j = 0; j < 4; ++j)
        acc[i][j] = __builtin_amdgcn_mfma_f32_16x16x32_bf16(af[i], bfr[j],
                                                            acc[i][j], 0, 0, 0);
  }

  const int colbase = tn * BM + wn;
  float bv[4];
#pragma unroll
  for (int j = 0; j < 4; ++j) bv[j] = bias[colbase + j * 16 + la];

  float* eps = (wave < 2) ? ((float*)As) + wave * 1024
                          : ((float*)Bs) + (wave - 2) * 1024;
  const int rowbase = tm * BM + wm;

#pragma unroll
  for (int i = 0; i < 4; ++i) {
    __syncthreads();
#pragma unroll
    for (int j = 0; j < 4; ++j)
#pragma unroll
      for (int r = 0; r < 4; ++r)
        eps[(quad * 4 + r) * 64 + j * 16 + la] = acc[i][j][r] + bv[j];
    __syncthreads();
#pragma unroll
    for (int s = 0; s < 4; ++s) {
      int idx = s * 64 + lane;
      int row = idx >> 4, c4 = idx & 15;
      float4 v = *(const float4*)(eps + row * 64 + c4 * 4);
      size_t goff = (size_t)(rowbase + i * 16 + row) * Nn + colbase + c4 * 4;
      if (OUT_F32) {
        *(float4*)((float*)Cout + goff) = v;
      } else {
        ushort4 u;
        u.x = bf16r(v.x); u.y = bf16r(v.y); u.z = bf16r(v.z); u.w = bf16r(v.w);
        *(ushort4*)((unsigned short*)Cout + goff) = u;
      }
    }
  }
}

// ---------------------------------------------------------------- fused
// Block = 64 rows {32 b x 2 n}, 512 threads (8 waves), grid 256 = 1 block/CU.
// Phase 1: q[64][1024] = query_rows @ Wq + bq, acc in regs (128 f32/lane),
//          Wq streamed from WqTile (2-phase double-buffered global_load_lds),
//          query f32 converted on the fly (reg-staged, ds_write_b64).
// Phase 2: wave w owns heads {2w, 2w+1} x both n -> 4 (n,h) pairs, each fully
//          wave-private (no barriers): repack q slice -> LDS, scores^T = R*q^T
//          (MFMA), in-reg softmax (2 shfl_xor), attn float4 stores, attn^T ->
//          LDS bf16, recv^T = R^T*attn^T (MFMA), recv bf16 stores.
// LDS (shorts): Bbuf0 @0 (32768) | Bbuf1 @32768 | Abuf0 @65536 (2048) |
//               Abuf1 @67584 ; total 69632 shorts = 136 KiB.
// Phase-2 overlay on Bbuf: per-wave scratch @ w*6144 (Qs 2304, AT @ +3072),
//               Rs0 @49152, Rs1 @53248, RTs0 @57344, RTs1 @61440.
__global__ __launch_bounds__(512, 2)
void fused_qmid(const float* __restrict__ query,          // (32,512,1024) f32
                const unsigned short* __restrict__ wqt,   // WqTile bf16
                const float* __restrict__ bq,
                const unsigned short* __restrict__ Rg,
                const unsigned short* __restrict__ RTg,
                float* __restrict__ attn_out,             // (B,H,N,S) f32
                unsigned short* __restrict__ recv_out) {  // (16384,1024) bf16
  __shared__ __align__(16) unsigned short lds[69632];
  const int tid = threadIdx.x, lane = tid & 63, w = tid >> 6;
  const int la = lane & 15, quad = lane >> 4;
  const int n0 = blockIdx.x * 2;

  // ---- phase 1 ------------------------------------------------------
  f32x4 acc[4][8] = {};   // [row-tile rt][col-tile j] ; rows rho = nl*32+b

  const int arow = tid >> 3;                  // rho 0..63
  const int ag   = tid & 7;                   // which 4-f32 group of 32 k
  const int a_b  = arow & 31, a_nl = arow >> 5;
  const float* aq = query + ((size_t)(a_b * 512 + n0 + a_nl)) * 1024 + ag * 4;
  const int a_lidx = (ag >> 1) * 512 + arow * 8 + (ag & 1) * 4; // Abuf short idx
  const int bslot  = w * 512 + lane * 8;      // linear staging slot (shorts)

  // prologue: stage kb=0 into buf0
  {
    float4 qv = *(const float4*)(aq);
#pragma unroll
    for (int p = 0; p < 8; ++p)
      async_ld16(wqt + p * 4096 + bslot, lds + p * 4096 + w * 512);
    ushort4 u;
    u.x = bf16r(qv.x); u.y = bf16r(qv.y); u.z = bf16r(qv.z); u.w = bf16r(qv.w);
    *(ushort4*)(lds + 65536 + a_lidx) = u;
  }
  __syncthreads();

#pragma unroll 1
  for (int kb = 0; kb < 32; ++kb) {
    const int cur = kb & 1;
    unsigned short* Bc_ = lds + cur * 32768;
    unsigned short* Ac_ = lds + 65536 + cur * 2048;
    unsigned short* Bn_ = lds + (cur ^ 1) * 32768;
    unsigned short* An_ = lds + 65536 + (cur ^ 1) * 2048;

    float4 qv;
    if (kb < 31) {                       // issue next-tile staging first
      qv = *(const float4*)(aq + (kb + 1) * 32);
#pragma unroll
      for (int p = 0; p < 8; ++p)
        async_ld16(wqt + (size_t)(kb + 1) * 32768 + p * 4096 + bslot,
                   Bn_ + p * 4096 + w * 512);
    }

    bf16x8 af[4], bfr[8];
#pragma unroll
    for (int rt = 0; rt < 4; ++rt)
      af[rt] = *(const bf16x8*)(Ac_ + quad * 512 + (rt * 16 + la) * 8);
#pragma unroll
    for (int j = 0; j < 8; ++j)
      bfr[j] = *(const bf16x8*)(Bc_ + quad * 8192 + ((w * 8 + j) * 16 + la) * 8);
#pragma unroll
    for (int rt = 0; rt < 4; ++rt)
#pragma unroll
      for (int j = 0; j < 8; ++j)
        acc[rt][j] = __builtin_amdgcn_mfma_f32_16x16x32_bf16(af[rt], bfr[j],
                                                             acc[rt][j], 0, 0, 0);
    if (kb < 31) {
      ushort4 u;
      u.x = bf16r(qv.x); u.y = bf16r(qv.y); u.z = bf16r(qv.z); u.w = bf16r(qv.w);
      *(ushort4*)(An_ + a_lidx) = u;
    }
    __syncthreads();                     // drains vmcnt: next buf ready
  }

  // bias (f32, before bf16 repack — same chain as old gemm1 epilogue)
  float bv[8];
#pragma unroll
  for (int j = 0; j < 8; ++j) bv[j] = bq[(w * 8 + j) * 16 + la];
#pragma unroll
  for (int rt = 0; rt < 4; ++rt)
#pragma unroll
    for (int j = 0; j < 8; ++j)
#pragma unroll
      for (int r = 0; r < 4; ++r) acc[rt][j][r] += bv[j];

  // ---- phase 2 staging: R/RT over (now dead) Bbuf region -------------
#pragma unroll
  for (int q2 = 0; q2 < 4; ++q2) {
    const unsigned short* srcb = (q2 < 2) ? (Rg  + (size_t)(n0 + q2)     * 4096)
                                          : (RTg + (size_t)(n0 + q2 - 2) * 4096);
    async_ld16(srcb + bslot, lds + 49152 + q2 * 4096 + w * 512);
  }
  __syncthreads();   // barrier waits vmcnt(0): R/RT staged, scratch free

  unsigned short* Qs = lds + w * 6144;          // [32 b][72] padded, 2-way free
  unsigned short* AT = lds + w * 6144 + 3072;   // [32 b][72]
  const unsigned short* Rsb  = lds + 49152;
  const unsigned short* RTsb = lds + 57344;

#pragma unroll
  for (int nl = 0; nl < 2; ++nl) {
#pragma unroll
    for (int hh = 0; hh < 2; ++hh) {
      const int h  = w * 2 + hh;
      const int nn = n0 + nl;

      // 1. repack this pair's q slice -> Qs (bf16) ; 32 scalar u16 writes
#pragma unroll
      for (int rt2 = 0; rt2 < 2; ++rt2)
#pragma unroll
        for (int j4 = 0; j4 < 4; ++j4)
#pragma unroll
          for (int r = 0; r < 4; ++r) {
            int b_ = rt2 * 16 + quad * 4 + r;
            int d_ = j4 * 16 + la;
            Qs[b_ * 72 + d_] = bf16r(acc[nl * 2 + rt2][hh * 4 + j4][r]);
          }

      // 2. frags (wave-private; compiler inserts lgkm waits)
      bf16x8 qf[2][2], rf[4][2];
#pragma unroll
      for (int bt = 0; bt < 2; ++bt)
#pragma unroll
        for (int kc = 0; kc < 2; ++kc)
          qf[bt][kc] = *(const bf16x8*)(Qs + (bt * 16 + la) * 72 + (kc * 4 + quad) * 8);
      const unsigned short* Rn = Rsb + nl * 4096;
#pragma unroll
      for (int st = 0; st < 4; ++st)
#pragma unroll
        for (int kc = 0; kc < 2; ++kc) {
          int s_ = st * 16 + la;
          rf[st][kc] = *(const bf16x8*)(Rn + s_ * 64 + ((kc * 4 + quad) ^ (s_ & 7)) * 8);
        }

      // 3. scores^T = R * q^T : rows s, cols b
      f32x4 sacc[2][4] = {};
#pragma unroll
      for (int bt = 0; bt < 2; ++bt)
#pragma unroll
        for (int st = 0; st < 4; ++st) {
          sacc[bt][st] = __builtin_amdgcn_mfma_f32_16x16x32_bf16(rf[st][0], qf[bt][0], sacc[bt][st], 0, 0, 0);
          sacc[bt][st] = __builtin_amdgcn_mfma_f32_16x16x32_bf16(rf[st][1], qf[bt][1], sacc[bt][st], 0, 0, 0);
        }

      // 4. softmax over s per column b; s lives in 16 regs x 4 quads
#pragma unroll
      for (int bt = 0; bt < 2; ++bt) {
        float mx = sacc[bt][0][0];
#pragma unroll
        for (int st = 0; st < 4; ++st)
#pragma unroll
          for (int r = 0; r < 4; ++r) mx = fmaxf(mx, sacc[bt][st][r]);
        mx = fmaxf(mx, __shfl_xor(mx, 16));
        mx = fmaxf(mx, __shfl_xor(mx, 32));
        float sum = 0.f;
#pragma unroll
        for (int st = 0; st < 4; ++st)
#pragma unroll
          for (int r = 0; r < 4; ++r) {
            float e = __expf(sacc[bt][st][r] - mx);
            sacc[bt][st][r] = e; sum += e;
          }
        sum += __shfl_xor(sum, 16);
        sum += __shfl_xor(sum, 32);
        float inv = 1.0f / sum;
#pragma unroll
        for (int st = 0; st < 4; ++st) {
          sacc[bt][st][0] *= inv; sacc[bt][st][1] *= inv;
          sacc[bt][st][2] *= inv; sacc[bt][st][3] *= inv;
        }
        const int b_ = bt * 16 + la;
        float* ao = attn_out + ((size_t)(b_ * 16 + h) * 512 + nn) * 64 + quad * 4;
#pragma unroll
        for (int st = 0; st < 4; ++st) {
          *(float4*)(ao + st * 16) = *(float4*)(&sacc[bt][st]);
          ushort4 u;
          u.x = bf16r(sacc[bt][st][0]); u.y = bf16r(sacc[bt][st][1]);
          u.z = bf16r(sacc[bt][st][2]); u.w = bf16r(sacc[bt][st][3]);
          *(ushort4*)(AT + b_ * 72 + st * 16 + quad * 4) = u;
        }
      }

      // 5. recv^T = R^T * attn^T : rows d, cols b
      bf16x8 atf[2][2], rtf2[4][2];
#pragma unroll
      for (int bt = 0; bt < 2; ++bt)
#pragma unroll
        for (int kc = 0; kc < 2; ++kc)
          atf[bt][kc] = *(const bf16x8*)(AT + (bt * 16 + la) * 72 + (kc * 4 + quad) * 8);
      const unsigned short* RTn = RTsb + nl * 4096;
#pragma unroll
      for (int dt = 0; dt < 4; ++dt)
#pragma unroll
        for (int kc = 0; kc < 2; ++kc) {
          int d_ = dt * 16 + la;
          rtf2[dt][kc] = *(const bf16x8*)(RTn + d_ * 64 + ((kc * 4 + quad) ^ (d_ & 7)) * 8);
        }
      f32x4 racc[2][4] = {};
#pragma unroll
      for (int bt = 0; bt < 2; ++bt)
#pragma unroll
        for (int dt = 0; dt < 4; ++dt) {
          racc[bt][dt] = __builtin_amdgcn_mfma_f32_16x16x32_bf16(rtf2[dt][0], atf[bt][0], racc[bt][dt], 0, 0, 0);
          racc[bt][dt] = __builtin_amdgcn_mfma_f32_16x16x32_bf16(rtf2[dt][1], atf[bt][1], racc[bt][dt], 0, 0, 0);
        }

      // 6. recv stores: element (b, d = dt*16+quad*4+r) -> row b*512+nn
#pragma unroll
      for (int bt = 0; bt < 2; ++bt) {
        const int b_ = bt * 16 + la;
        unsigned short* ro = recv_out + ((size_t)(b_ * 512 + nn)) * 1024
                           + h * 64 + quad * 4;
#pragma unroll
        for (int dt = 0; dt < 4; ++dt) {
          ushort4 u;
          u.x = bf16r(racc[bt][dt][0]); u.y = bf16r(racc[bt][dt][1]);
          u.z = bf16r(racc[bt][dt][2]); u.w = bf16r(racc[bt][dt][3]);
          *(ushort4*)(ro + dt * 16) = u;
        }
      }
    }
  }
}

// ---------------------------------------------------------------- launch
extern "C" void kernel_launch(void* const* d_in, const int* in_sizes, int n_in,
                              void* d_out, int out_size, void* d_ws, size_t ws_size,
                              hipStream_t stream) {
  const float* query  = (const float*)d_in[0];
  const float* router = (const float*)d_in[3];
  const float* Wq     = (const float*)d_in[4];
  const float* bq     = (const float*)d_in[5];
  const float* Wo     = (const float*)d_in[10];
  const float* bo     = (const float*)d_in[11];

  float* out      = (float*)d_out;                       // (B,N,D) f32
  float* attn_out = out + (size_t)Bc * Nc * Dc;          // (B,H,N,S) f32

  char* ws = (char*)d_ws;
  unsigned short* recv_b = (unsigned short*)(ws);                  // 32 MiB
  unsigned short* WqTile = (unsigned short*)(ws + 33554432u);      // 2 MiB
  unsigned short* WoT    = (unsigned short*)(ws + 35651584u);      // 2 MiB
  unsigned short* Rg     = (unsigned short*)(ws + 37748736u);      // 4 MiB
  unsigned short* RTg    = (unsigned short*)(ws + 41943040u);      // 4 MiB

  wq_tile       <<<1024, 256, 0, stream>>>(Wq, WqTile);
  transpose_bf16<<<1024, 256, 0, stream>>>(Wo, WoT);
  cvt_router2   <<<512,  256, 0, stream>>>(router, Rg, RTg);
  fused_qmid    <<<256,  512, 0, stream>>>(query, WqTile, bq, Rg, RTg,
                                           attn_out, recv_b);
  gemm_bt<true> <<<(Mrows / 128) * 8, 256, 0, stream>>>(recv_b, WoT, bo, out);
}